// Round 12
// baseline (256.647 us; speedup 1.0000x reference)
//
#include <hip/hip_runtime.h>

#define NB 256      // batch
#define NC 512      // codebooks
#define NK 1024     // codes per book
#define NE 64      // embedding dim
#define MH 128      // batch rows per block (b-half)
#define NT 16       // k-tiles
#define KTILE 64    // k per tile
#define LDR 256     // bytes per COMPACT row [seg0|seg1] (R8-validated layout)

typedef float f32x4 __attribute__((ext_vector_type(4)));
typedef short short8 __attribute__((ext_vector_type(8)));

// LDS-ordering barrier without the vmcnt(0) drain (__syncthreads would drain
// the streaming one_hot stores every tile).
#define LGKM_BARRIER() do {                                   \
    asm volatile("s_waitcnt lgkmcnt(0)" ::: "memory");        \
    __builtin_amdgcn_s_barrier();                             \
    __builtin_amdgcn_sched_barrier(0);                        \
} while (0)

__device__ __forceinline__ unsigned short b16rn(float x) {
    unsigned u = __float_as_uint(x);
    unsigned r = (u + 0x7FFFu + ((u >> 16) & 1u)) >> 16;
    return (unsigned short)r;
}
__device__ __forceinline__ float b16f(unsigned short h) {
    return __uint_as_float(((unsigned)h) << 16);
}

// 2-way bf16 split; compact LDS row [s0(128B) | s1(128B)].
// Logical K'=192 (A=[A0|A0|A1], B=[B0|B1|B0]) reconstructed at read time
// (R8-validated: MFMA inputs bit-identical to R7's kernel).
__device__ __forceinline__ void write_splits2(char* rowbase, int qbyte, int swz,
                                              const float v[8]) {
    short8 s0, s1;
#pragma unroll
    for (int e = 0; e < 8; ++e) {
        unsigned short h0 = b16rn(v[e]);
        float r1 = v[e] - b16f(h0);      // exact (Sterbenz)
        s0[e] = (short)h0;
        s1[e] = (short)b16rn(r1);
    }
    *(short8*)(rowbase + ((qbyte +   0) ^ swz)) = s0;
    *(short8*)(rowbase + ((qbyte + 128) ^ swz)) = s1;
}

// d2 EXACTLY as the validated R1/R7 kernels (FROZEN — knife-edge pair at
// ~1e-5 in this dataset; this formula is the one that lands right).
__device__ __forceinline__ float d2_tree(const float* __restrict__ dr) {
    float part[16];
#pragma unroll
    for (int cidx = 0; cidx < 16; ++cidx) {
        float x = dr[4 * cidx + 0], y = dr[4 * cidx + 1];
        float zv = dr[4 * cidx + 2], w = dr[4 * cidx + 3];
        float s = x * x;
        s = fmaf(y, y, s);
        s = fmaf(zv, zv, s);
        s = fmaf(w, w, s);
        part[cidx] = s;
    }
#pragma unroll
    for (int lvl = 1; lvl < 16; lvl <<= 1)
#pragma unroll
        for (int j = 0; j < 16; j += 2 * lvl)
            part[j] = part[j] + part[j + lvl];
    return part[0];
}

// Block (c, half): dots[128 b x 1024 k] via bf16-split MFMA (K'=192).
// R12 = R10 structure (best: 171.5us) with (1) all output stores PLAIN
// instead of nontemporal — the 6.7-6.9 TB/s ceiling was measured on the
// harness fill kernel which uses plain stores (L2 line-aggregated
// writeback); nt bypasses L2 and may throttle the write path; (2) A-frag
// dedup [6][2]->[4][2] (ks 2,3 alias ks 0,1 — same bits, -16 VGPR).
__global__ __launch_bounds__(512, 2)
void vq_mfma(const float* __restrict__ mu, const float* __restrict__ dict,
             float* __restrict__ z, float* __restrict__ z_embed,
             float* __restrict__ one_hot)
{
    const int c    = blockIdx.x;
    const int half = blockIdx.y;
    const int tid  = threadIdx.x;
    const int lane = tid & 63;
    const int wid  = tid >> 6;
    const int mq   = wid & 3;     // which 32-row group
    const int kh   = wid >> 2;    // which 32-k half of the tile

    __shared__ __align__(16) char As[MH * LDR];         // 32 KB
    __shared__ __align__(16) char Bs[2][KTILE * LDR];   // 2 x 16 KB
    __shared__ float d2t[2][KTILE];
    __shared__ float Wd1[2][MH]; __shared__ int Wk1[2][MH];
    __shared__ float Wd2[2][MH]; __shared__ int Wk2[2][MH];
    __shared__ int finalk_sh[MH];

    const float*  dictc = dict + (size_t)c * NK * NE;
    const float4* dict4 = (const float4*)dictc;
    const int b0 = half * MH;

    // ---- stage A once (compact): 128 rows x 8 e-chunks ----
    for (int u = tid; u < MH * 8; u += 512) {
        int bb = u >> 3, q = u & 7;
        const float* src = mu + (size_t)(b0 + bb) * (NC * NE) + (size_t)c * NE + q * 8;
        float4 v0 = ((const float4*)src)[0];
        float4 v1 = ((const float4*)src)[1];
        float v[8] = {v0.x, v0.y, v0.z, v0.w, v1.x, v1.y, v1.z, v1.w};
        write_splits2(As + bb * LDR, q * 16, (bb & 7) << 4, v);
    }

    // ---- stage B tile 0 into Bs[0] + d2t[0] ----
    const int krow = tid >> 3, qq = tid & 7;
    {
        const float* src = dictc + (size_t)krow * NE + qq * 8;
        float4 r0 = ((const float4*)src)[0];
        float4 r1 = ((const float4*)src)[1];
        float v[8] = {r0.x, r0.y, r0.z, r0.w, r1.x, r1.y, r1.z, r1.w};
        write_splits2(Bs[0] + krow * LDR, qq * 16, (krow & 7) << 4, v);
        float p = 0.f;
#pragma unroll
        for (int e = 0; e < 8; ++e) p = fmaf(v[e], v[e], p);
        p += __shfl_xor(p, 1, 64);
        p += __shfl_xor(p, 2, 64);
        p += __shfl_xor(p, 4, 64);
        if (qq == 0) d2t[0][krow] = p;
    }
    LGKM_BARRIER();

    const int l15 = lane & 15;
    const int lg  = lane >> 4;

    // ---- hoist A fragments (4 unique chunks x 2 m; ks2,3 alias ks0,1) ----
    short8 afr[4][2];
#pragma unroll
    for (int ch = 0; ch < 4; ++ch) {
        int aoff = ch * 64 + lg * 16;   // s0c0, s0c1, s1c0, s1c1
#pragma unroll
        for (int m = 0; m < 2; ++m) {
            int row = mq * 32 + m * 16 + l15;
            afr[ch][m] = *(const short8*)(As + row * LDR + (aoff ^ ((row & 7) << 4)));
        }
    }

    float bd1[8], bd2[8]; int bk1[8], bk2[8];
#pragma unroll
    for (int s = 0; s < 8; ++s) { bd1[s] = 3.4e38f; bd2[s] = 3.4e38f; bk1[s] = 0; bk2[s] = 0; }

    for (int nt = 0; nt < NT; ++nt) {
        const int cur = nt & 1;
        // prefetch next B tile (latency hides under MFMA phase)
        float4 n0, n1;
        if (nt + 1 < NT) {
            const float* src = dictc + ((size_t)(nt + 1) * KTILE + krow) * NE + qq * 8;
            n0 = ((const float4*)src)[0];
            n1 = ((const float4*)src)[1];
        }
        // zero one_hot: wave wid zeroes row nt*8+wid fully (4KB linear, PLAIN)
        {
            const f32x4 zero4 = (f32x4)(0.f);
            int row = nt * 8 + wid;           // 16 tiles x 8 waves = 128 rows
            size_t base4 = ((size_t)(b0 + row) * (NC * NK) + (size_t)c * NK) / 4;
#pragma unroll
            for (int ii = 0; ii < 4; ++ii)
                ((f32x4*)one_hot)[base4 + (size_t)ii * 64 + lane] = zero4;
        }
        // ---- MFMA: 6 K'-steps x (2 M x 2 N); B from LDS, A from regs.
        //      ks->A chunk: {0,1,0,1,2,3} (logical [A0|A0|A1]);
        //      ks->B boff remap [B0|B1|B0]: ks<4 id, else -256. Order FROZEN. ----
        f32x4 acc[2][2];
#pragma unroll
        for (int m = 0; m < 2; ++m)
#pragma unroll
            for (int n = 0; n < 2; ++n) acc[m][n] = (f32x4)(0.f);

#pragma unroll
        for (int ks = 0; ks < 6; ++ks) {
            const int AKS = (ks < 2) ? ks : ((ks < 4) ? ks - 2 : ks - 2);
            int ebyte = ks * 64 + lg * 16;
            int boff  = (ks < 4) ? ebyte : (ebyte - 256);
            short8 bf[2];
#pragma unroll
            for (int n = 0; n < 2; ++n) {
                int row = kh * 32 + n * 16 + l15;
                bf[n] = *(const short8*)(Bs[cur] + row * LDR + (boff ^ ((row & 7) << 4)));
            }
#pragma unroll
            for (int m = 0; m < 2; ++m)
#pragma unroll
                for (int n = 0; n < 2; ++n)
                    acc[m][n] = __builtin_amdgcn_mfma_f32_16x16x32_bf16(
                                    afr[AKS][m], bf[n], acc[m][n], 0, 0, 0);
        }
        // ---- approx scores + per-lane best-2 (ties keep earlier k) ----
#pragma unroll
        for (int n = 0; n < 2; ++n) {
            int klocal = kh * 32 + n * 16 + l15;
            float dv = d2t[cur][klocal];
            int kk = nt * KTILE + klocal;
#pragma unroll
            for (int m = 0; m < 2; ++m)
#pragma unroll
                for (int i = 0; i < 4; ++i) {
                    float s = fmaf(-2.0f, acc[m][n][i], dv);
                    int slot2 = m * 4 + i;
                    bool u1 = s < bd1[slot2];
                    bool u2 = s < bd2[slot2];
                    bd2[slot2] = u1 ? bd1[slot2] : (u2 ? s : bd2[slot2]);
                    bk2[slot2] = u1 ? bk1[slot2] : (u2 ? kk : bk2[slot2]);
                    bd1[slot2] = u1 ? s : bd1[slot2];
                    bk1[slot2] = u1 ? kk : bk1[slot2];
                }
        }
        // ---- stage next tile into the OTHER buffer, then ONE barrier ----
        if (nt + 1 < NT) {
            float v[8] = {n0.x, n0.y, n0.z, n0.w, n1.x, n1.y, n1.z, n1.w};
            write_splits2(Bs[cur ^ 1] + krow * LDR, qq * 16, (krow & 7) << 4, v);
            float p = 0.f;
#pragma unroll
            for (int e = 0; e < 8; ++e) p = fmaf(v[e], v[e], p);
            p += __shfl_xor(p, 1, 64);
            p += __shfl_xor(p, 2, 64);
            p += __shfl_xor(p, 4, 64);
            if (qq == 0) d2t[cur ^ 1][krow] = p;
        }
        LGKM_BARRIER();
    }

    // ---- in-wave butterfly: merge best-2 across the 16 k-lanes ----
#pragma unroll
    for (int mask = 1; mask <= 8; mask <<= 1) {
#pragma unroll
        for (int s = 0; s < 8; ++s) {
            float od1 = __shfl_xor(bd1[s], mask, 64);
            int   ok1 = __shfl_xor(bk1[s], mask, 64);
            float od2 = __shfl_xor(bd2[s], mask, 64);
            int   ok2 = __shfl_xor(bk2[s], mask, 64);
            bool bf_ = (od1 < bd1[s]) || (od1 == bd1[s] && ok1 < bk1[s]);
            float w1d = bf_ ? od1 : bd1[s]; int w1k = bf_ ? ok1 : bk1[s];
            float l1d = bf_ ? bd1[s] : od1; int l1k = bf_ ? bk1[s] : ok1;
            float c2d = bf_ ? od2 : bd2[s]; int c2k = bf_ ? ok2 : bk2[s];
            bool sf_ = (l1d < c2d) || (l1d == c2d && l1k < c2k);
            bd1[s] = w1d; bk1[s] = w1k;
            bd2[s] = sf_ ? l1d : c2d; bk2[s] = sf_ ? l1k : c2k;
        }
    }
    if (l15 == 0) {
#pragma unroll
        for (int s = 0; s < 8; ++s) {
            int m = s >> 2, i = s & 3;
            int bb = mq * 32 + m * 16 + lg * 4 + i;
            Wd1[kh][bb] = bd1[s]; Wk1[kh][bb] = bk1[s];
            Wd2[kh][bb] = bd2[s]; Wk2[kh][bb] = bk2[s];
        }
    }
    __syncthreads();   // full drain: all one_hot zeros committed here

    // ---- merge k-halves, exact fp32 recompute of both candidates (FROZEN) ----
    if (tid < MH) {
        int bb = tid;
        float da  = Wd1[0][bb], d2a = Wd2[0][bb];
        int   ka  = Wk1[0][bb], k2a = Wk2[0][bb];
        float db_ = Wd1[1][bb], d2b = Wd2[1][bb];
        int   kb  = Wk1[1][bb], k2b = Wk2[1][bb];
        bool bf_ = (db_ < da) || (db_ == da && kb < ka);
        float l1d = bf_ ? da : db_;  int l1k = bf_ ? ka : kb;
        int   w1k = bf_ ? kb : ka;
        float c2d = bf_ ? d2b : d2a; int c2k = bf_ ? k2b : k2a;
        bool sf_ = (l1d < c2d) || (l1d == c2d && l1k < c2k);
        int w2k = sf_ ? l1k : c2k;
        int ka_ = min(w1k, w2k), kb2 = max(w1k, w2k);

        const float* mr = mu + (size_t)(b0 + bb) * (NC * NE) + (size_t)c * NE;
        float m2 = 0.f;
        for (int e = 0; e < NE; ++e) m2 = fmaf(mr[e], mr[e], m2);
        const float* dr1 = dictc + (size_t)ka_ * NE;
        const float* dr2 = dictc + (size_t)kb2 * NE;
        float dot1 = 0.f, dot2 = 0.f;
        for (int e = 0; e < NE; ++e) {
            float me = mr[e];
            dot1 = fmaf(me, dr1[e], dot1);
            dot2 = fmaf(me, dr2[e], dot2);
        }
        float dd1 = d2_tree(dr1);
        float dd2 = d2_tree(dr2);
        float e1 = (m2 - 2.f * dot1) + dd1;
        float e2 = (m2 - 2.f * dot2) + dd2;
        int fk = (e2 < e1) ? kb2 : ka_;   // tie -> lower k
        finalk_sh[bb] = fk;
        one_hot[(size_t)(b0 + bb) * (NC * NK) + (size_t)c * NK + fk] = 1.0f;
    }
    __syncthreads();

    // ---- gather z / z_embed (16 lanes cover one 256B dict row), PLAIN ----
#pragma unroll
    for (int ii = 0; ii < 4; ++ii) {
        int i  = tid + 512 * ii;          // 0..2047
        int b2 = i >> 4, cc = i & 15;
        float4 vv = dict4[(size_t)finalk_sh[b2] * 16 + cc];
        f32x4 v; v.x = vv.x; v.y = vv.y; v.z = vv.z; v.w = vv.w;
        size_t off = ((size_t)(b0 + b2) * (NC * NE) + (size_t)c * NE) / 4 + cc;
        ((f32x4*)z)[off]       = v;
        ((f32x4*)z_embed)[off] = v;
    }
}

extern "C" void kernel_launch(void* const* d_in, const int* in_sizes, int n_in,
                              void* d_out, int out_size, void* d_ws, size_t ws_size,
                              hipStream_t stream) {
    const float* mu   = (const float*)d_in[0];
    const float* dict = (const float*)d_in[1];
    float* z       = (float*)d_out;
    float* z_embed = (float*)d_out + (size_t)NB * NC * NE;
    float* one_hot = (float*)d_out + (size_t)2 * NB * NC * NE;
    vq_mfma<<<dim3(NC, 2), dim3(512), 0, stream>>>(mu, dict, z, z_embed, one_hot);
}

// Round 13
// 171.033 us; speedup vs baseline: 1.5006x; 1.5006x over previous
//
#include <hip/hip_runtime.h>

#define NB 256      // batch
#define NC 512      // codebooks
#define NK 1024     // codes per book
#define NE 64       // embedding dim
#define MH 128      // batch rows per block (b-half)
#define NT 16       // k-tiles
#define KTILE 64    // k per tile
#define LDR 256     // bytes per COMPACT row [seg0|seg1] (R8-validated layout)

typedef float f32x4 __attribute__((ext_vector_type(4)));
typedef short short8 __attribute__((ext_vector_type(8)));

// LDS-ordering barrier without the vmcnt(0) drain (__syncthreads would drain
// the streaming nontemporal one_hot stores every tile).
#define LGKM_BARRIER() do {                                   \
    asm volatile("s_waitcnt lgkmcnt(0)" ::: "memory");        \
    __builtin_amdgcn_s_barrier();                             \
    __builtin_amdgcn_sched_barrier(0);                        \
} while (0)

__device__ __forceinline__ unsigned short b16rn(float x) {
    unsigned u = __float_as_uint(x);
    unsigned r = (u + 0x7FFFu + ((u >> 16) & 1u)) >> 16;
    return (unsigned short)r;
}
__device__ __forceinline__ float b16f(unsigned short h) {
    return __uint_as_float(((unsigned)h) << 16);
}

// 2-way bf16 split; compact LDS row [s0(128B) | s1(128B)].
// Logical K'=192 (A=[A0|A0|A1], B=[B0|B1|B0]) reconstructed at read time
// (R8-validated: MFMA inputs bit-identical to R7's kernel).
__device__ __forceinline__ void write_splits2(char* rowbase, int qbyte, int swz,
                                              const float v[8]) {
    short8 s0, s1;
#pragma unroll
    for (int e = 0; e < 8; ++e) {
        unsigned short h0 = b16rn(v[e]);
        float r1 = v[e] - b16f(h0);      // exact (Sterbenz)
        s0[e] = (short)h0;
        s1[e] = (short)b16rn(r1);
    }
    *(short8*)(rowbase + ((qbyte +   0) ^ swz)) = s0;
    *(short8*)(rowbase + ((qbyte + 128) ^ swz)) = s1;
}

// d2 EXACTLY as the validated R1/R7 kernels (FROZEN — knife-edge pair at
// ~1e-5 in this dataset; this formula is the one that lands right).
__device__ __forceinline__ float d2_tree(const float* __restrict__ dr) {
    float part[16];
#pragma unroll
    for (int cidx = 0; cidx < 16; ++cidx) {
        float x = dr[4 * cidx + 0], y = dr[4 * cidx + 1];
        float zv = dr[4 * cidx + 2], w = dr[4 * cidx + 3];
        float s = x * x;
        s = fmaf(y, y, s);
        s = fmaf(zv, zv, s);
        s = fmaf(w, w, s);
        part[cidx] = s;
    }
#pragma unroll
    for (int lvl = 1; lvl < 16; lvl <<= 1)
#pragma unroll
        for (int j = 0; j < 16; j += 2 * lvl)
            part[j] = part[j] + part[j + lvl];
    return part[0];
}

// Block (c, half): dots[128 b x 1024 k] via bf16-split MFMA (K'=192).
// R13 = R10 structure restored (171.5us best): NONTEMPORAL output stores
// (R12 proved plain stores thrash L2: 256us, -50%); A-hoist to regs;
// Bs double-buffered compact, ONE lgkm-barrier per tile; best-2 + frozen
// exact recompute. afr dedup [4][2] kept from R12 (bit-identical operands).
__global__ __launch_bounds__(512, 2)
void vq_mfma(const float* __restrict__ mu, const float* __restrict__ dict,
             float* __restrict__ z, float* __restrict__ z_embed,
             float* __restrict__ one_hot)
{
    const int c    = blockIdx.x;
    const int half = blockIdx.y;
    const int tid  = threadIdx.x;
    const int lane = tid & 63;
    const int wid  = tid >> 6;
    const int mq   = wid & 3;     // which 32-row group
    const int kh   = wid >> 2;    // which 32-k half of the tile

    __shared__ __align__(16) char As[MH * LDR];         // 32 KB
    __shared__ __align__(16) char Bs[2][KTILE * LDR];   // 2 x 16 KB
    __shared__ float d2t[2][KTILE];
    __shared__ float Wd1[2][MH]; __shared__ int Wk1[2][MH];
    __shared__ float Wd2[2][MH]; __shared__ int Wk2[2][MH];
    __shared__ int finalk_sh[MH];

    const float*  dictc = dict + (size_t)c * NK * NE;
    const float4* dict4 = (const float4*)dictc;
    const int b0 = half * MH;

    // ---- stage A once (compact): 128 rows x 8 e-chunks ----
    for (int u = tid; u < MH * 8; u += 512) {
        int bb = u >> 3, q = u & 7;
        const float* src = mu + (size_t)(b0 + bb) * (NC * NE) + (size_t)c * NE + q * 8;
        float4 v0 = ((const float4*)src)[0];
        float4 v1 = ((const float4*)src)[1];
        float v[8] = {v0.x, v0.y, v0.z, v0.w, v1.x, v1.y, v1.z, v1.w};
        write_splits2(As + bb * LDR, q * 16, (bb & 7) << 4, v);
    }

    // ---- stage B tile 0 into Bs[0] + d2t[0] ----
    const int krow = tid >> 3, qq = tid & 7;
    {
        const float* src = dictc + (size_t)krow * NE + qq * 8;
        float4 r0 = ((const float4*)src)[0];
        float4 r1 = ((const float4*)src)[1];
        float v[8] = {r0.x, r0.y, r0.z, r0.w, r1.x, r1.y, r1.z, r1.w};
        write_splits2(Bs[0] + krow * LDR, qq * 16, (krow & 7) << 4, v);
        float p = 0.f;
#pragma unroll
        for (int e = 0; e < 8; ++e) p = fmaf(v[e], v[e], p);
        p += __shfl_xor(p, 1, 64);
        p += __shfl_xor(p, 2, 64);
        p += __shfl_xor(p, 4, 64);
        if (qq == 0) d2t[0][krow] = p;
    }
    LGKM_BARRIER();

    const int l15 = lane & 15;
    const int lg  = lane >> 4;

    // ---- hoist A fragments (4 unique chunks x 2 m; ks2,3 alias ks0,1) ----
    short8 afr[4][2];
#pragma unroll
    for (int ch = 0; ch < 4; ++ch) {
        int aoff = ch * 64 + lg * 16;   // s0c0, s0c1, s1c0, s1c1
#pragma unroll
        for (int m = 0; m < 2; ++m) {
            int row = mq * 32 + m * 16 + l15;
            afr[ch][m] = *(const short8*)(As + row * LDR + (aoff ^ ((row & 7) << 4)));
        }
    }

    float bd1[8], bd2[8]; int bk1[8], bk2[8];
#pragma unroll
    for (int s = 0; s < 8; ++s) { bd1[s] = 3.4e38f; bd2[s] = 3.4e38f; bk1[s] = 0; bk2[s] = 0; }

    for (int nt = 0; nt < NT; ++nt) {
        const int cur = nt & 1;
        // prefetch next B tile (latency hides under MFMA phase)
        float4 n0, n1;
        if (nt + 1 < NT) {
            const float* src = dictc + ((size_t)(nt + 1) * KTILE + krow) * NE + qq * 8;
            n0 = ((const float4*)src)[0];
            n1 = ((const float4*)src)[1];
        }
        // zero one_hot: wave wid zeroes row nt*8+wid fully (4KB linear, NT)
        {
            const f32x4 zero4 = (f32x4)(0.f);
            int row = nt * 8 + wid;           // 16 tiles x 8 waves = 128 rows
            size_t base4 = ((size_t)(b0 + row) * (NC * NK) + (size_t)c * NK) / 4;
#pragma unroll
            for (int ii = 0; ii < 4; ++ii)
                __builtin_nontemporal_store(zero4,
                    &((f32x4*)one_hot)[base4 + (size_t)ii * 64 + lane]);
        }
        // ---- MFMA: 6 K'-steps x (2 M x 2 N); B from LDS, A from regs.
        //      ks->A chunk {0,1,0,1,2,3}; ks->B boff [B0|B1|B0] remap. FROZEN. ----
        f32x4 acc[2][2];
#pragma unroll
        for (int m = 0; m < 2; ++m)
#pragma unroll
            for (int n = 0; n < 2; ++n) acc[m][n] = (f32x4)(0.f);

#pragma unroll
        for (int ks = 0; ks < 6; ++ks) {
            const int AKS = (ks < 2) ? ks : ks - 2;
            int ebyte = ks * 64 + lg * 16;
            int boff  = (ks < 4) ? ebyte : (ebyte - 256);
            short8 bf[2];
#pragma unroll
            for (int n = 0; n < 2; ++n) {
                int row = kh * 32 + n * 16 + l15;
                bf[n] = *(const short8*)(Bs[cur] + row * LDR + (boff ^ ((row & 7) << 4)));
            }
#pragma unroll
            for (int m = 0; m < 2; ++m)
#pragma unroll
                for (int n = 0; n < 2; ++n)
                    acc[m][n] = __builtin_amdgcn_mfma_f32_16x16x32_bf16(
                                    afr[AKS][m], bf[n], acc[m][n], 0, 0, 0);
        }
        // ---- approx scores + per-lane best-2 (ties keep earlier k) ----
#pragma unroll
        for (int n = 0; n < 2; ++n) {
            int klocal = kh * 32 + n * 16 + l15;
            float dv = d2t[cur][klocal];
            int kk = nt * KTILE + klocal;
#pragma unroll
            for (int m = 0; m < 2; ++m)
#pragma unroll
                for (int i = 0; i < 4; ++i) {
                    float s = fmaf(-2.0f, acc[m][n][i], dv);
                    int slot2 = m * 4 + i;
                    bool u1 = s < bd1[slot2];
                    bool u2 = s < bd2[slot2];
                    bd2[slot2] = u1 ? bd1[slot2] : (u2 ? s : bd2[slot2]);
                    bk2[slot2] = u1 ? bk1[slot2] : (u2 ? kk : bk2[slot2]);
                    bd1[slot2] = u1 ? s : bd1[slot2];
                    bk1[slot2] = u1 ? kk : bk1[slot2];
                }
        }
        // ---- stage next tile into the OTHER buffer, then ONE barrier ----
        if (nt + 1 < NT) {
            float v[8] = {n0.x, n0.y, n0.z, n0.w, n1.x, n1.y, n1.z, n1.w};
            write_splits2(Bs[cur ^ 1] + krow * LDR, qq * 16, (krow & 7) << 4, v);
            float p = 0.f;
#pragma unroll
            for (int e = 0; e < 8; ++e) p = fmaf(v[e], v[e], p);
            p += __shfl_xor(p, 1, 64);
            p += __shfl_xor(p, 2, 64);
            p += __shfl_xor(p, 4, 64);
            if (qq == 0) d2t[cur ^ 1][krow] = p;
        }
        LGKM_BARRIER();
    }

    // ---- in-wave butterfly: merge best-2 across the 16 k-lanes ----
#pragma unroll
    for (int mask = 1; mask <= 8; mask <<= 1) {
#pragma unroll
        for (int s = 0; s < 8; ++s) {
            float od1 = __shfl_xor(bd1[s], mask, 64);
            int   ok1 = __shfl_xor(bk1[s], mask, 64);
            float od2 = __shfl_xor(bd2[s], mask, 64);
            int   ok2 = __shfl_xor(bk2[s], mask, 64);
            bool bf_ = (od1 < bd1[s]) || (od1 == bd1[s] && ok1 < bk1[s]);
            float w1d = bf_ ? od1 : bd1[s]; int w1k = bf_ ? ok1 : bk1[s];
            float l1d = bf_ ? bd1[s] : od1; int l1k = bf_ ? bk1[s] : ok1;
            float c2d = bf_ ? od2 : bd2[s]; int c2k = bf_ ? ok2 : bk2[s];
            bool sf_ = (l1d < c2d) || (l1d == c2d && l1k < c2k);
            bd1[s] = w1d; bk1[s] = w1k;
            bd2[s] = sf_ ? l1d : c2d; bk2[s] = sf_ ? l1k : c2k;
        }
    }
    if (l15 == 0) {
#pragma unroll
        for (int s = 0; s < 8; ++s) {
            int m = s >> 2, i = s & 3;
            int bb = mq * 32 + m * 16 + lg * 4 + i;
            Wd1[kh][bb] = bd1[s]; Wk1[kh][bb] = bk1[s];
            Wd2[kh][bb] = bd2[s]; Wk2[kh][bb] = bk2[s];
        }
    }
    __syncthreads();   // full drain: all one_hot zeros committed here

    // ---- merge k-halves, exact fp32 recompute of both candidates (FROZEN) ----
    if (tid < MH) {
        int bb = tid;
        float da  = Wd1[0][bb], d2a = Wd2[0][bb];
        int   ka  = Wk1[0][bb], k2a = Wk2[0][bb];
        float db_ = Wd1[1][bb], d2b = Wd2[1][bb];
        int   kb  = Wk1[1][bb], k2b = Wk2[1][bb];
        bool bf_ = (db_ < da) || (db_ == da && kb < ka);
        float l1d = bf_ ? da : db_;  int l1k = bf_ ? ka : kb;
        int   w1k = bf_ ? kb : ka;
        float c2d = bf_ ? d2b : d2a; int c2k = bf_ ? k2b : k2a;
        bool sf_ = (l1d < c2d) || (l1d == c2d && l1k < c2k);
        int w2k = sf_ ? l1k : c2k;
        int ka_ = min(w1k, w2k), kb2 = max(w1k, w2k);

        const float* mr = mu + (size_t)(b0 + bb) * (NC * NE) + (size_t)c * NE;
        float m2 = 0.f;
        for (int e = 0; e < NE; ++e) m2 = fmaf(mr[e], mr[e], m2);
        const float* dr1 = dictc + (size_t)ka_ * NE;
        const float* dr2 = dictc + (size_t)kb2 * NE;
        float dot1 = 0.f, dot2 = 0.f;
        for (int e = 0; e < NE; ++e) {
            float me = mr[e];
            dot1 = fmaf(me, dr1[e], dot1);
            dot2 = fmaf(me, dr2[e], dot2);
        }
        float dd1 = d2_tree(dr1);
        float dd2 = d2_tree(dr2);
        float e1 = (m2 - 2.f * dot1) + dd1;
        float e2 = (m2 - 2.f * dot2) + dd2;
        int fk = (e2 < e1) ? kb2 : ka_;   // tie -> lower k
        finalk_sh[bb] = fk;
        one_hot[(size_t)(b0 + bb) * (NC * NK) + (size_t)c * NK + fk] = 1.0f;
    }
    __syncthreads();

    // ---- gather z / z_embed (16 lanes cover one 256B dict row), NT ----
#pragma unroll
    for (int ii = 0; ii < 4; ++ii) {
        int i  = tid + 512 * ii;          // 0..2047
        int b2 = i >> 4, cc = i & 15;
        float4 vv = dict4[(size_t)finalk_sh[b2] * 16 + cc];
        f32x4 v; v.x = vv.x; v.y = vv.y; v.z = vv.z; v.w = vv.w;
        size_t off = ((size_t)(b0 + b2) * (NC * NE) + (size_t)c * NE) / 4 + cc;
        __builtin_nontemporal_store(v, &((f32x4*)z)[off]);
        __builtin_nontemporal_store(v, &((f32x4*)z_embed)[off]);
    }
}

extern "C" void kernel_launch(void* const* d_in, const int* in_sizes, int n_in,
                              void* d_out, int out_size, void* d_ws, size_t ws_size,
                              hipStream_t stream) {
    const float* mu   = (const float*)d_in[0];
    const float* dict = (const float*)d_in[1];
    float* z       = (float*)d_out;
    float* z_embed = (float*)d_out + (size_t)NB * NC * NE;
    float* one_hot = (float*)d_out + (size_t)2 * NB * NC * NE;
    vq_mfma<<<dim3(NC, 2), dim3(512), 0, stream>>>(mu, dict, z, z_embed, one_hot);
}